// Round 3
// baseline (96.790 us; speedup 1.0000x reference)
//
#include <hip/hip_runtime.h>
#include <hip/hip_bf16.h>

// Problem constants (from the reference)
constexpr int B = 16, C = 2, H = 512, W = 512;
constexpr int HW = H * W;                    // 262144 pixels per batch
constexpr int BLOCKS_PER_BATCH = 128;        // 2048 pixels per block
constexpr int NBLK = B * BLOCKS_PER_BATCH;   // 2048 blocks
constexpr int THREADS = 256;                 // 8 pixels per thread (2 x float4)
constexpr float BG_WEIGHT = 0.4f;

// Workspace layout (floats):
//   ws[0      .. NBLK)    per-block entropy partial
//   ws[NBLK   .. 2*NBLK)  per-block fg squared-error partial
//   ws[2*NBLK .. 3*NBLK)  per-block fg count partial
//   ws[3*NBLK]            arrival counter (uint, memset to 0 each launch)
__global__ __launch_bounds__(THREADS) void coloss_fused(
    const float* __restrict__ conf,   // [B,2,H,W]
    const float* __restrict__ off,    // [B,2,H,W]
    const int*   __restrict__ inst,   // [B,1,H,W]
    const float* __restrict__ gto,    // [B,2,H,W]
    float* __restrict__ ws,
    float* __restrict__ out)
{
    const int b   = blockIdx.x / BLOCKS_PER_BATCH;
    const int blk = blockIdx.x % BLOCKS_PER_BATCH;

    const float* conf0 = conf + (size_t)b * C * HW;
    const float* conf1 = conf0 + HW;
    const float* off0  = off  + (size_t)b * 2 * HW;
    const float* off1  = off0 + HW;
    const float* gt0   = gto  + (size_t)b * 2 * HW;
    const float* gt1   = gt0 + HW;
    const int*   ins   = inst + (size_t)b * HW;

    const int vecBase = blk * (2048 / 4);    // float4 index within batch

    float entAcc = 0.f;
    float sqAcc  = 0.f;
    int   cnt    = 0;

    #pragma unroll
    for (int it = 0; it < 2; ++it) {
        const int p4 = vecBase + it * THREADS + threadIdx.x;
        const float4 c0 = ((const float4*)conf0)[p4];
        const float4 c1 = ((const float4*)conf1)[p4];
        const float4 o0 = ((const float4*)off0)[p4];
        const float4 o1 = ((const float4*)off1)[p4];
        const float4 g0 = ((const float4*)gt0)[p4];
        const float4 g1 = ((const float4*)gt1)[p4];
        const int4   iv = ((const int4*)ins)[p4];

        const float cc0[4] = {c0.x, c0.y, c0.z, c0.w};
        const float cc1[4] = {c1.x, c1.y, c1.z, c1.w};
        const float oo0[4] = {o0.x, o0.y, o0.z, o0.w};
        const float oo1[4] = {o1.x, o1.y, o1.z, o1.w};
        const float gg0[4] = {g0.x, g0.y, g0.z, g0.w};
        const float gg1[4] = {g1.x, g1.y, g1.z, g1.w};
        const int   ii[4]  = {iv.x, iv.y, iv.z, iv.w};

        #pragma unroll
        for (int j = 0; j < 4; ++j) {
            const bool fg = (ii[j] != 0);
            const float gathered = fg ? cc1[j] : cc0[j];
            float e = -__logf(gathered);
            e *= fg ? 1.0f : BG_WEIGHT;
            entAcc += e;
            const float d0 = gg0[j] - oo0[j];
            const float d1 = gg1[j] - oo1[j];
            const float t  = d0 * d0 + d1 * d1;
            if (fg) { sqAcc += t; cnt += 1; }
        }
    }

    // wave (64-lane) butterfly reduce
    float fcnt = (float)cnt;
    #pragma unroll
    for (int m = 32; m >= 1; m >>= 1) {
        entAcc += __shfl_xor(entAcc, m, 64);
        sqAcc  += __shfl_xor(sqAcc,  m, 64);
        fcnt   += __shfl_xor(fcnt,   m, 64);
    }

    __shared__ float sEnt[4], sSq[4], sCnt[4];
    __shared__ int sLast;
    const int wave = threadIdx.x >> 6;
    const int lane = threadIdx.x & 63;
    if (lane == 0) { sEnt[wave] = entAcc; sSq[wave] = sqAcc; sCnt[wave] = fcnt; }
    __syncthreads();

    if (threadIdx.x == 0) {
        const int g = blockIdx.x;
        ws[g]            = sEnt[0] + sEnt[1] + sEnt[2] + sEnt[3];
        ws[NBLK + g]     = sSq[0]  + sSq[1]  + sSq[2]  + sSq[3];
        ws[2 * NBLK + g] = sCnt[0] + sCnt[1] + sCnt[2] + sCnt[3];
        __threadfence();   // release: partials visible device-wide before arrival
        const unsigned old = atomicAdd((unsigned*)(ws + 3 * NBLK), 1u);
        sLast = (old == (unsigned)(NBLK - 1)) ? 1 : 0;
    }
    __syncthreads();
    if (!sLast) return;

    // ---- last block: finalize (all 2048 partials are visible) ----
    __threadfence();       // acquire

    const float* entp = ws;
    const float* sqp  = ws + NBLK;
    const float* cntp = ws + 2 * NBLK;

    float e = 0.f;
    for (int i = threadIdx.x; i < NBLK; i += THREADS) e += entp[i];

    const int bb = threadIdx.x >> 4;      // 0..15
    const int t  = threadIdx.x & 15;      // 0..15
    float s = 0.f, c = 0.f;
    for (int i = t; i < BLOCKS_PER_BATCH; i += 16) {
        s += sqp[bb * BLOCKS_PER_BATCH + i];
        c += cntp[bb * BLOCKS_PER_BATCH + i];
    }
    #pragma unroll
    for (int m = 8; m >= 1; m >>= 1) {
        s += __shfl_xor(s, m, 64);
        c += __shfl_xor(c, m, 64);
    }
    __shared__ float sRatio[16];
    if (t == 0) sRatio[bb] = (c > 0.f) ? (s / c) : 0.f;

    #pragma unroll
    for (int m = 32; m >= 1; m >>= 1) e += __shfl_xor(e, m, 64);
    __shared__ float sE[4];
    if (lane == 0) sE[wave] = e;
    __syncthreads();

    if (threadIdx.x == 0) {
        const float ent = sE[0] + sE[1] + sE[2] + sE[3];
        float off_loss = 0.f;
        #pragma unroll
        for (int i = 0; i < B; ++i) off_loss += sRatio[i];
        out[0] = ent / (float)((size_t)B * HW) + off_loss / (float)B;
    }
}

extern "C" void kernel_launch(void* const* d_in, const int* in_sizes, int n_in,
                              void* d_out, int out_size, void* d_ws, size_t ws_size,
                              hipStream_t stream) {
    const float* conf = (const float*)d_in[0];
    const float* off  = (const float*)d_in[1];
    const int*   inst = (const int*)d_in[2];
    const float* gto  = (const float*)d_in[3];
    float* out = (float*)d_out;
    float* ws  = (float*)d_ws;

    // zero the arrival counter (harness poisons d_ws once; counter must start 0)
    hipMemsetAsync(ws + 3 * NBLK, 0, sizeof(unsigned), stream);

    coloss_fused<<<dim3(NBLK), dim3(THREADS), 0, stream>>>(conf, off, inst, gto, ws, out);
}

// Round 4
// 27.128 us; speedup vs baseline: 3.5678x; 3.5678x over previous
//
#include <hip/hip_runtime.h>
#include <hip/hip_bf16.h>

// Problem constants (from the reference)
constexpr int B = 16, C = 2, H = 512, W = 512;
constexpr int HW = H * W;                    // 262144 pixels per batch
constexpr int BLOCKS_PER_BATCH = 128;        // 2048 pixels per block
constexpr int NBLK = B * BLOCKS_PER_BATCH;   // 2048 blocks
constexpr int THREADS = 256;                 // 8 pixels per thread (2 x float4)
constexpr float BG_WEIGHT = 0.4f;

// Workspace layout (floats):
//   ws[0      .. NBLK)    per-block entropy partial
//   ws[NBLK   .. 2*NBLK)  per-block fg squared-error partial
//   ws[2*NBLK .. 3*NBLK)  per-block fg count partial
// Every slot is unconditionally written each launch -> no zeroing needed.
__global__ __launch_bounds__(THREADS) void coloss_reduce(
    const float* __restrict__ conf,   // [B,2,H,W]
    const float* __restrict__ off,    // [B,2,H,W]
    const int*   __restrict__ inst,   // [B,1,H,W]
    const float* __restrict__ gto,    // [B,2,H,W]
    float* __restrict__ ws)
{
    const int b   = blockIdx.x / BLOCKS_PER_BATCH;
    const int blk = blockIdx.x % BLOCKS_PER_BATCH;

    const float* conf0 = conf + (size_t)b * C * HW;
    const float* conf1 = conf0 + HW;
    const float* off0  = off  + (size_t)b * 2 * HW;
    const float* off1  = off0 + HW;
    const float* gt0   = gto  + (size_t)b * 2 * HW;
    const float* gt1   = gt0 + HW;
    const int*   ins   = inst + (size_t)b * HW;

    const int pA = blk * (2048 / 4) + threadIdx.x;   // float4 index, group A
    const int pB = pA + THREADS;                     // group B

    // ---- issue ALL 14 loads before any compute (max memory-level parallelism) ----
    const float4 c0A = ((const float4*)conf0)[pA];
    const float4 c1A = ((const float4*)conf1)[pA];
    const float4 o0A = ((const float4*)off0)[pA];
    const float4 o1A = ((const float4*)off1)[pA];
    const float4 g0A = ((const float4*)gt0)[pA];
    const float4 g1A = ((const float4*)gt1)[pA];
    const int4   ivA = ((const int4*)ins)[pA];
    const float4 c0B = ((const float4*)conf0)[pB];
    const float4 c1B = ((const float4*)conf1)[pB];
    const float4 o0B = ((const float4*)off0)[pB];
    const float4 o1B = ((const float4*)off1)[pB];
    const float4 g0B = ((const float4*)gt0)[pB];
    const float4 g1B = ((const float4*)gt1)[pB];
    const int4   ivB = ((const int4*)ins)[pB];

    float entAcc = 0.f;
    float sqAcc  = 0.f;
    float fcnt   = 0.f;

    auto accum = [&](float cc0, float cc1, float oo0, float oo1,
                     float gg0, float gg1, int ii) {
        const bool fg = (ii != 0);
        const float gathered = fg ? cc1 : cc0;
        float e = -__logf(gathered);
        e *= fg ? 1.0f : BG_WEIGHT;
        entAcc += e;
        const float d0 = gg0 - oo0;
        const float d1 = gg1 - oo1;
        const float t  = d0 * d0 + d1 * d1;
        if (fg) { sqAcc += t; fcnt += 1.0f; }
    };

    accum(c0A.x, c1A.x, o0A.x, o1A.x, g0A.x, g1A.x, ivA.x);
    accum(c0A.y, c1A.y, o0A.y, o1A.y, g0A.y, g1A.y, ivA.y);
    accum(c0A.z, c1A.z, o0A.z, o1A.z, g0A.z, g1A.z, ivA.z);
    accum(c0A.w, c1A.w, o0A.w, o1A.w, g0A.w, g1A.w, ivA.w);
    accum(c0B.x, c1B.x, o0B.x, o1B.x, g0B.x, g1B.x, ivB.x);
    accum(c0B.y, c1B.y, o0B.y, o1B.y, g0B.y, g1B.y, ivB.y);
    accum(c0B.z, c1B.z, o0B.z, o1B.z, g0B.z, g1B.z, ivB.z);
    accum(c0B.w, c1B.w, o0B.w, o1B.w, g0B.w, g1B.w, ivB.w);

    // wave (64-lane) butterfly reduce
    #pragma unroll
    for (int m = 32; m >= 1; m >>= 1) {
        entAcc += __shfl_xor(entAcc, m, 64);
        sqAcc  += __shfl_xor(sqAcc,  m, 64);
        fcnt   += __shfl_xor(fcnt,   m, 64);
    }

    __shared__ float sEnt[4], sSq[4], sCnt[4];
    const int wave = threadIdx.x >> 6;
    const int lane = threadIdx.x & 63;
    if (lane == 0) { sEnt[wave] = entAcc; sSq[wave] = sqAcc; sCnt[wave] = fcnt; }
    __syncthreads();

    if (threadIdx.x == 0) {
        const int g = blockIdx.x;
        ws[g]            = sEnt[0] + sEnt[1] + sEnt[2] + sEnt[3];
        ws[NBLK + g]     = sSq[0]  + sSq[1]  + sSq[2]  + sSq[3];
        ws[2 * NBLK + g] = sCnt[0] + sCnt[1] + sCnt[2] + sCnt[3];
    }
}

__global__ __launch_bounds__(256) void coloss_finalize(const float* __restrict__ ws,
                                                       float* __restrict__ out)
{
    const float* entp = ws;
    const float* sqp  = ws + NBLK;
    const float* cntp = ws + 2 * NBLK;

    // --- entropy: sum all 2048 partials across the block ---
    float e = 0.f;
    for (int i = threadIdx.x; i < NBLK; i += 256) e += entp[i];

    // --- per-batch sq/cnt: 16 threads per batch, 8 entries each ---
    const int b = threadIdx.x >> 4;       // 0..15
    const int t = threadIdx.x & 15;       // 0..15
    float s = 0.f, c = 0.f;
    for (int i = t; i < BLOCKS_PER_BATCH; i += 16) {
        s += sqp[b * BLOCKS_PER_BATCH + i];
        c += cntp[b * BLOCKS_PER_BATCH + i];
    }
    #pragma unroll
    for (int m = 8; m >= 1; m >>= 1) {    // reduce within 16-lane subgroup
        s += __shfl_xor(s, m, 64);
        c += __shfl_xor(c, m, 64);
    }
    __shared__ float sRatio[16];
    if (t == 0) sRatio[b] = (c > 0.f) ? (s / c) : 0.f;

    // entropy wave reduce + cross-wave via LDS
    #pragma unroll
    for (int m = 32; m >= 1; m >>= 1) e += __shfl_xor(e, m, 64);
    __shared__ float sE[4];
    if ((threadIdx.x & 63) == 0) sE[threadIdx.x >> 6] = e;
    __syncthreads();

    if (threadIdx.x == 0) {
        const float ent = sE[0] + sE[1] + sE[2] + sE[3];
        float off_loss = 0.f;
        #pragma unroll
        for (int i = 0; i < B; ++i) off_loss += sRatio[i];
        out[0] = ent / (float)((size_t)B * HW) + off_loss / (float)B;
    }
}

extern "C" void kernel_launch(void* const* d_in, const int* in_sizes, int n_in,
                              void* d_out, int out_size, void* d_ws, size_t ws_size,
                              hipStream_t stream) {
    const float* conf = (const float*)d_in[0];
    const float* off  = (const float*)d_in[1];
    const int*   inst = (const int*)d_in[2];
    const float* gto  = (const float*)d_in[3];
    float* out = (float*)d_out;
    float* ws  = (float*)d_ws;

    coloss_reduce<<<dim3(NBLK), dim3(THREADS), 0, stream>>>(conf, off, inst, gto, ws);
    coloss_finalize<<<1, 256, 0, stream>>>(ws, out);
}

// Round 5
// 26.482 us; speedup vs baseline: 3.6549x; 1.0244x over previous
//
#include <hip/hip_runtime.h>
#include <hip/hip_bf16.h>

// Problem constants (from the reference)
constexpr int B = 16, C = 2, H = 512, W = 512;
constexpr int HW = H * W;                    // 262144 pixels per batch
constexpr int BLOCKS_PER_BATCH = 32;         // 8192 pixels per block
constexpr int NBLK = B * BLOCKS_PER_BATCH;   // 512 blocks
constexpr int THREADS = 256;
constexpr int VEC_PER_BLOCK = (HW / BLOCKS_PER_BATCH) / 4;       // 2048 float4 groups
constexpr int ITERS = VEC_PER_BLOCK / (2 * THREADS);             // 4 iters of 2 groups
constexpr float BG_WEIGHT = 0.4f;

// Workspace layout (floats):
//   ws[0      .. NBLK)    per-block entropy partial
//   ws[NBLK   .. 2*NBLK)  per-block fg squared-error partial
//   ws[2*NBLK .. 3*NBLK)  per-block fg count partial
// Every slot is unconditionally written each launch -> no zeroing needed.
__global__ __launch_bounds__(THREADS) void coloss_reduce(
    const float* __restrict__ conf,   // [B,2,H,W]
    const float* __restrict__ off,    // [B,2,H,W]
    const int*   __restrict__ inst,   // [B,1,H,W]
    const float* __restrict__ gto,    // [B,2,H,W]
    float* __restrict__ ws)
{
    const int b   = blockIdx.x / BLOCKS_PER_BATCH;
    const int blk = blockIdx.x % BLOCKS_PER_BATCH;

    const float* conf0 = conf + (size_t)b * C * HW;
    const float* conf1 = conf0 + HW;
    const float* off0  = off  + (size_t)b * 2 * HW;
    const float* off1  = off0 + HW;
    const float* gt0   = gto  + (size_t)b * 2 * HW;
    const float* gt1   = gt0 + HW;
    const int*   ins   = inst + (size_t)b * HW;

    const int base = blk * VEC_PER_BLOCK;     // float4 index of this block's chunk

    float entAcc = 0.f;
    float sqAcc  = 0.f;
    float fcnt   = 0.f;

    auto accum = [&](float cc0, float cc1, float oo0, float oo1,
                     float gg0, float gg1, int ii) {
        const bool fg = (ii != 0);
        const float gathered = fg ? cc1 : cc0;
        float e = -__logf(gathered);
        e *= fg ? 1.0f : BG_WEIGHT;
        entAcc += e;
        const float d0 = gg0 - oo0;
        const float d1 = gg1 - oo1;
        const float t  = d0 * d0 + d1 * d1;
        if (fg) { sqAcc += t; fcnt += 1.0f; }
    };

    #pragma unroll 2
    for (int it = 0; it < ITERS; ++it) {
        const int pA = base + it * (2 * THREADS) + threadIdx.x;
        const int pB = pA + THREADS;

        // issue all 14 loads of this iteration before any compute
        const float4 c0A = ((const float4*)conf0)[pA];
        const float4 c1A = ((const float4*)conf1)[pA];
        const float4 o0A = ((const float4*)off0)[pA];
        const float4 o1A = ((const float4*)off1)[pA];
        const float4 g0A = ((const float4*)gt0)[pA];
        const float4 g1A = ((const float4*)gt1)[pA];
        const int4   ivA = ((const int4*)ins)[pA];
        const float4 c0B = ((const float4*)conf0)[pB];
        const float4 c1B = ((const float4*)conf1)[pB];
        const float4 o0B = ((const float4*)off0)[pB];
        const float4 o1B = ((const float4*)off1)[pB];
        const float4 g0B = ((const float4*)gt0)[pB];
        const float4 g1B = ((const float4*)gt1)[pB];
        const int4   ivB = ((const int4*)ins)[pB];

        accum(c0A.x, c1A.x, o0A.x, o1A.x, g0A.x, g1A.x, ivA.x);
        accum(c0A.y, c1A.y, o0A.y, o1A.y, g0A.y, g1A.y, ivA.y);
        accum(c0A.z, c1A.z, o0A.z, o1A.z, g0A.z, g1A.z, ivA.z);
        accum(c0A.w, c1A.w, o0A.w, o1A.w, g0A.w, g1A.w, ivA.w);
        accum(c0B.x, c1B.x, o0B.x, o1B.x, g0B.x, g1B.x, ivB.x);
        accum(c0B.y, c1B.y, o0B.y, o1B.y, g0B.y, g1B.y, ivB.y);
        accum(c0B.z, c1B.z, o0B.z, o1B.z, g0B.z, g1B.z, ivB.z);
        accum(c0B.w, c1B.w, o0B.w, o1B.w, g0B.w, g1B.w, ivB.w);
    }

    // wave (64-lane) butterfly reduce
    #pragma unroll
    for (int m = 32; m >= 1; m >>= 1) {
        entAcc += __shfl_xor(entAcc, m, 64);
        sqAcc  += __shfl_xor(sqAcc,  m, 64);
        fcnt   += __shfl_xor(fcnt,   m, 64);
    }

    __shared__ float sEnt[4], sSq[4], sCnt[4];
    const int wave = threadIdx.x >> 6;
    const int lane = threadIdx.x & 63;
    if (lane == 0) { sEnt[wave] = entAcc; sSq[wave] = sqAcc; sCnt[wave] = fcnt; }
    __syncthreads();

    if (threadIdx.x == 0) {
        const int g = blockIdx.x;
        ws[g]            = sEnt[0] + sEnt[1] + sEnt[2] + sEnt[3];
        ws[NBLK + g]     = sSq[0]  + sSq[1]  + sSq[2]  + sSq[3];
        ws[2 * NBLK + g] = sCnt[0] + sCnt[1] + sCnt[2] + sCnt[3];
    }
}

__global__ __launch_bounds__(256) void coloss_finalize(const float* __restrict__ ws,
                                                       float* __restrict__ out)
{
    const float* entp = ws;
    const float* sqp  = ws + NBLK;
    const float* cntp = ws + 2 * NBLK;

    // --- entropy: sum all NBLK partials across the block ---
    float e = 0.f;
    #pragma unroll
    for (int i = threadIdx.x; i < NBLK; i += 256) e += entp[i];

    // --- per-batch sq/cnt: 16 threads per batch ---
    const int b = threadIdx.x >> 4;       // 0..15
    const int t = threadIdx.x & 15;       // 0..15
    float s = 0.f, c = 0.f;
    #pragma unroll
    for (int i = t; i < BLOCKS_PER_BATCH; i += 16) {
        s += sqp[b * BLOCKS_PER_BATCH + i];
        c += cntp[b * BLOCKS_PER_BATCH + i];
    }
    #pragma unroll
    for (int m = 8; m >= 1; m >>= 1) {    // reduce within 16-lane subgroup
        s += __shfl_xor(s, m, 64);
        c += __shfl_xor(c, m, 64);
    }
    __shared__ float sRatio[16];
    if (t == 0) sRatio[b] = (c > 0.f) ? (s / c) : 0.f;

    // entropy wave reduce + cross-wave via LDS
    #pragma unroll
    for (int m = 32; m >= 1; m >>= 1) e += __shfl_xor(e, m, 64);
    __shared__ float sE[4];
    if ((threadIdx.x & 63) == 0) sE[threadIdx.x >> 6] = e;
    __syncthreads();

    if (threadIdx.x == 0) {
        const float ent = sE[0] + sE[1] + sE[2] + sE[3];
        float off_loss = 0.f;
        #pragma unroll
        for (int i = 0; i < B; ++i) off_loss += sRatio[i];
        out[0] = ent / (float)((size_t)B * HW) + off_loss / (float)B;
    }
}

extern "C" void kernel_launch(void* const* d_in, const int* in_sizes, int n_in,
                              void* d_out, int out_size, void* d_ws, size_t ws_size,
                              hipStream_t stream) {
    const float* conf = (const float*)d_in[0];
    const float* off  = (const float*)d_in[1];
    const int*   inst = (const int*)d_in[2];
    const float* gto  = (const float*)d_in[3];
    float* out = (float*)d_out;
    float* ws  = (float*)d_ws;

    coloss_reduce<<<dim3(NBLK), dim3(THREADS), 0, stream>>>(conf, off, inst, gto, ws);
    coloss_finalize<<<1, 256, 0, stream>>>(ws, out);
}